// Round 3
// baseline (61.272 us; speedup 1.0000x reference)
//
#include <hip/hip_runtime.h>
#include <hip/hip_bf16.h>

// Problem constants (S4Layer: T=4096, B=16, D=128, S=256)
#define T_  4096
#define B_  16
#define D_  128
#define S_  256
#define WND 64             // chunk length = GEMM t-tile
#define C4  (T_/WND)       // 64 chunks

using bf8   = __attribute__((ext_vector_type(8))) short;   // 8 bf16 (4 VGPRs)
using f32x4 = __attribute__((ext_vector_type(4))) float;   // MFMA acc

__device__ inline float rnd_bf(float f) {   // round through bf16 (matches scan input)
    return __bfloat162float(__float2bfloat16(f));
}

// ---------------- K1: parameters -------------------------------------------
// blocks 0..127: bbar[s][d] = ratio[s]*b[s][d] in bf16 ;  block 128: abar, a^64
__global__ __launch_bounds__(256) void k_params(
        const float* __restrict__ lna, const float* __restrict__ bmat,
        const float* __restrict__ ldt,
        float* __restrict__ abar, float* __restrict__ a64,
        __hip_bfloat16* __restrict__ bbar) {
    if (blockIdx.x < 128) {
        int idx = blockIdx.x * 256 + threadIdx.x;   // (s,d)
        int s = idx >> 7;
        float la = fminf(fmaxf(lna[s], -8.f), 4.f);
        float ar = -expf(la);
        float lt = fminf(fmaxf(ldt[s], -8.f), 1.f);
        float dt = expf(lt);
        float xx = dt * ar;
        float ratio = (fabsf(xx) < 1e-6f) ? dt : (expm1f(xx) / ar);
        bbar[idx] = __float2bfloat16(ratio * bmat[idx]);
    } else {
        int s = threadIdx.x;
        float la = fminf(fmaxf(lna[s], -8.f), 4.f);
        float ar = -expf(la);
        float lt = fminf(fmaxf(ldt[s], -8.f), 1.f);
        float dt = expf(lt);
        float ab = expf(dt * ar);
        abar[s] = ab;
        float p = ab;
#pragma unroll
        for (int j = 0; j < 6; ++j) p *= p;     // a^64 by squaring
        a64[s] = p;
    }
}

// Shared GEMM core: block (c,b) computes acc[i][j] for wave-tile 64t x 64s.
// Wave w owns s in [w*64, w*64+64); lane l15 -> s offset, l4*4+r -> t row.
#define GEMM_CORE(ALS)                                                        \
    const int tid = threadIdx.x, lane = tid & 63, w = tid >> 6;               \
    const int l15 = lane & 15, l4 = lane >> 4;                                \
    bf8 bfrag[4][4];                                                          \
    _Pragma("unroll")                                                         \
    for (int j = 0; j < 4; ++j) {                                             \
        int s = w * 64 + j * 16 + l15;                                        \
        _Pragma("unroll")                                                     \
        for (int kk = 0; kk < 4; ++kk)                                        \
            bfrag[j][kk] = *(const bf8*)((const short*)bbar + s * D_ + kk * 32 + l4 * 8); \
    }                                                                         \
    for (int idx = tid; idx < WND * 32; idx += 256) {                         \
        int row = idx >> 5, seg = idx & 31;                                   \
        float4 v = *(const float4*)(x + ((size_t)(t0 + row) * B_ + b) * D_ + seg * 4); \
        __hip_bfloat162 lo = __float22bfloat162_rn(make_float2(v.x, v.y));    \
        __hip_bfloat162 hi = __float22bfloat162_rn(make_float2(v.z, v.w));    \
        uint2 pk = { *(unsigned*)&lo, *(unsigned*)&hi };                      \
        int off = (row * 256 + seg * 8) ^ ((row & 7) << 4);                   \
        *(uint2*)(ALS + off) = pk;                                            \
    }                                                                         \
    __syncthreads();                                                          \
    f32x4 acc[4][4] = {};                                                     \
    _Pragma("unroll")                                                         \
    for (int i = 0; i < 4; ++i) {                                             \
        bf8 af[4];                                                            \
        int tr = i * 16 + l15;                                                \
        _Pragma("unroll")                                                     \
        for (int kk = 0; kk < 4; ++kk) {                                      \
            int off = (tr * 256 + kk * 64 + l4 * 16) ^ ((tr & 7) << 4);       \
            af[kk] = *(const bf8*)(ALS + off);                                \
        }                                                                     \
        _Pragma("unroll")                                                     \
        for (int j = 0; j < 4; ++j)                                           \
            _Pragma("unroll")                                                 \
            for (int kk = 0; kk < 4; ++kk)                                    \
                acc[i][j] = __builtin_amdgcn_mfma_f32_16x16x32_bf16(          \
                                af[kk], bfrag[j][kk], acc[i][j], 0, 0, 0);    \
    }

// ---------------- K_A: chunk end-states only -------------------------------
// e64[c,b,s] = sum_{t<64} a^(63-t) * bf16(ub[c*64+t, b, s])
__global__ __launch_bounds__(256, 2) void k_e64(
        const float* __restrict__ x, const __hip_bfloat16* __restrict__ bbar,
        const float* __restrict__ abar, float* __restrict__ e64) {
    const int c = blockIdx.x, b = blockIdx.y;
    const int t0 = c * WND;
    __shared__ char Als[WND * 256];   // 16 KiB swizzled A tile
    GEMM_CORE(Als)
    // weight a^(63-t), t = i*16 + l4*4 + r  =>  a^(3-r) * a^(16*(3-i)) * a^(12-4*l4)
#pragma unroll
    for (int j = 0; j < 4; ++j) {
        int s = w * 64 + j * 16 + l15;
        float a  = abar[s];
        float a2 = a * a, a4 = a2 * a2, a8 = a4 * a4, a16 = a8 * a8;
        float lf = (l4 == 0) ? a8 * a4 : (l4 == 1) ? a8 : (l4 == 2) ? a4 : 1.f;
        float e = 0.f;
#pragma unroll
        for (int i = 0; i < 4; ++i) {
            float inner = rnd_bf(acc[i][j][0]);
            inner = fmaf(inner, a, rnd_bf(acc[i][j][1]));
            inner = fmaf(inner, a, rnd_bf(acc[i][j][2]));
            inner = fmaf(inner, a, rnd_bf(acc[i][j][3]));
            e = fmaf(e, a16, inner);
        }
        e *= lf;
        e += __shfl_xor(e, 16);
        e += __shfl_xor(e, 32);
        if (l4 == 0) e64[((size_t)c * B_ + b) * S_ + s] = e;
    }
}

// ---------------- K_B: carry scan across 64 chunks -------------------------
__global__ __launch_bounds__(256) void k_carry(
        const float* __restrict__ e64, const float* __restrict__ a64,
        const float* __restrict__ z0, float* __restrict__ cin) {
    int b = blockIdx.x, s = threadIdx.x;
    float aw = a64[s];
    float Z = z0[b * S_ + s];
    for (int c = 0; c < C4; ++c) {
        cin[((size_t)c * B_ + b) * S_ + s] = Z;
        Z = fmaf(aw, Z, e64[((size_t)c * B_ + b) * S_ + s]);
    }
}

// ---------------- K_C: recompute GEMM tile + scan + output -----------------
__global__ __launch_bounds__(256, 2) void k_scan(
        const float* __restrict__ x, const __hip_bfloat16* __restrict__ bbar,
        const float* __restrict__ abar, const float* __restrict__ cin,
        float* __restrict__ out) {
    const int c = blockIdx.x, b = blockIdx.y;
    const int t0 = c * WND;
    __shared__ char Als[WND * 256];   // 16 KiB swizzled A tile
    __shared__ char Pls[WND * 512];   // 32 KiB P[t][s] bf16, swizzled
    GEMM_CORE(Als)
    // P -> LDS (bf16, swizzle ^((t>>2&3)<<5): conflict-free write & read)
#pragma unroll
    for (int i = 0; i < 4; ++i)
#pragma unroll
        for (int j = 0; j < 4; ++j) {
            int s = w * 64 + j * 16 + l15;
#pragma unroll
            for (int r = 0; r < 4; ++r) {
                int t = i * 16 + l4 * 4 + r;
                int off = (t * 512 + s * 2) ^ (((t >> 2) & 3) << 5);
                __hip_bfloat162 one;
                *(unsigned short*)(Pls + off) =
                    __hip_bfloat16_raw(__float2bfloat16(acc[i][j][r])).x;
                (void)one;
            }
        }
    __syncthreads();
    // scan: thread = s
    int s = tid;
    float a = abar[s];
    float z = cin[((size_t)c * B_ + b) * S_ + s];
    float* op = out + ((size_t)t0 * B_ + b) * S_ + s;
#pragma unroll 16
    for (int t = 0; t < WND; ++t) {
        int off = (t * 512 + s * 2) ^ (((t >> 2) & 3) << 5);
        unsigned short h = *(unsigned short*)(Pls + off);
        z = fmaf(a, z, __builtin_bit_cast(float, (unsigned)h << 16));
        *op = z;
        op += (size_t)B_ * S_;
    }
}

extern "C" void kernel_launch(void* const* d_in, const int* in_sizes, int n_in,
                              void* d_out, int out_size, void* d_ws, size_t ws_size,
                              hipStream_t stream) {
    const float* x   = (const float*)d_in[0];  // [T,B,D]
    const float* z0  = (const float*)d_in[1];  // [B,S]
    const float* lna = (const float*)d_in[2];  // [S]
    const float* bm  = (const float*)d_in[3];  // [S,D]
    const float* ldt = (const float*)d_in[4];  // [S]
    float* out = (float*)d_out;

    char* ws = (char*)d_ws;
    float*          abar = (float*)ws;                              // 1 KiB
    float*          a64  = (float*)(ws + 4096);                     // 1 KiB
    __hip_bfloat16* bbar = (__hip_bfloat16*)(ws + 8192);            // 64 KiB
    float*          e64  = (float*)(ws + (128 << 10));              // 1 MiB
    float*          cin  = (float*)(ws + (128 << 10) + (1 << 20));  // 1 MiB

    k_params<<<129, 256, 0, stream>>>(lna, bm, ldt, abar, a64, bbar);
    k_e64<<<dim3(C4, B_), 256, 0, stream>>>(x, bbar, abar, e64);
    k_carry<<<B_, 256, 0, stream>>>(e64, a64, z0, cin);
    k_scan<<<dim3(C4, B_), 256, 0, stream>>>(x, bbar, abar, cin, out);
}